// Round 1
// baseline (1015.470 us; speedup 1.0000x reference)
//
#include <hip/hip_runtime.h>

#define T_TOK 8192
#define DIN   4096
#define DOUTF 4096
#define RANK  16
#define NADP  8

typedef __attribute__((ext_vector_type(4))) float f32x4;
typedef __attribute__((ext_vector_type(8))) short bf16x8;
typedef __attribute__((ext_vector_type(8))) unsigned short u16x8;

#define GLB_PTR(p) ((const __attribute__((address_space(1))) void*)(p))
#define LDS_PTR(p) ((__attribute__((address_space(3))) void*)(p))

__device__ __forceinline__ unsigned short f2bf(float f) {
  unsigned u = __float_as_uint(f);
  u = (u + 0x7fffu + ((u >> 16) & 1u)) >> 16;  // RNE
  return (unsigned short)u;
}

// ---------------------------------------------------------------- fp32 -> bf16
__global__ __launch_bounds__(256) void cvt_f32_bf16(const float* __restrict__ in,
                                                    unsigned short* __restrict__ out,
                                                    int n8) {
  const int stride = gridDim.x * blockDim.x;
  for (int i = blockIdx.x * blockDim.x + threadIdx.x; i < n8; i += stride) {
    const float4* p = (const float4*)(in + (size_t)i * 8);
    float4 a = p[0], b = p[1];
    u16x8 r;
    r[0] = f2bf(a.x); r[1] = f2bf(a.y); r[2] = f2bf(a.z); r[3] = f2bf(a.w);
    r[4] = f2bf(b.x); r[5] = f2bf(b.y); r[6] = f2bf(b.z); r[7] = f2bf(b.w);
    *(u16x8*)(out + (size_t)i * 8) = r;
  }
}

// ------------------------------------------------- h'[t,r] = scaling * x @ wa[id_t]
// block = 256 threads = 4 waves; each wave handles 4 consecutive tokens.
__global__ __launch_bounds__(256) void lora_h(const float* __restrict__ x,
                                              const float* __restrict__ wa,
                                              const float* __restrict__ scaling,
                                              const int* __restrict__ segment,
                                              const int* __restrict__ lora_ids,
                                              float* __restrict__ hbuf,
                                              int* __restrict__ tokid) {
  const int lane = threadIdx.x & 63;
  const int wave = threadIdx.x >> 6;
  const int t0 = blockIdx.x * 16 + wave * 4;

  int ids[4]; float sc[4];
#pragma unroll
  for (int q = 0; q < 4; ++q) {
    int t = t0 + q;
    int s = 0;
#pragma unroll
    for (int i = 1; i < 8; ++i)
      if (t >= segment[i]) s = i;
    int id = lora_ids[s];
    ids[q] = id;
    sc[q] = scaling[id];
  }

  float acc[4][16];
#pragma unroll
  for (int q = 0; q < 4; ++q)
#pragma unroll
    for (int r = 0; r < 16; ++r) acc[q][r] = 0.f;

  const bool same = (ids[0] == ids[1]) && (ids[1] == ids[2]) && (ids[2] == ids[3]);
  if (same) {
    const float* wrow = wa + (size_t)ids[0] * DIN * RANK;
    const float* xr0 = x + (size_t)(t0 + 0) * DIN;
    const float* xr1 = x + (size_t)(t0 + 1) * DIN;
    const float* xr2 = x + (size_t)(t0 + 2) * DIN;
    const float* xr3 = x + (size_t)(t0 + 3) * DIN;
    for (int d = lane; d < DIN; d += 64) {
      float xv[4] = {xr0[d], xr1[d], xr2[d], xr3[d]};
      const float4* wp = (const float4*)(wrow + (size_t)d * RANK);
      float4 w0 = wp[0], w1 = wp[1], w2 = wp[2], w3 = wp[3];
      float wv[16] = {w0.x, w0.y, w0.z, w0.w, w1.x, w1.y, w1.z, w1.w,
                      w2.x, w2.y, w2.z, w2.w, w3.x, w3.y, w3.z, w3.w};
#pragma unroll
      for (int q = 0; q < 4; ++q)
#pragma unroll
        for (int r = 0; r < 16; ++r) acc[q][r] += xv[q] * wv[r];
    }
  } else {
#pragma unroll
    for (int q = 0; q < 4; ++q) {
      const float* wrow = wa + (size_t)ids[q] * DIN * RANK;
      const float* xr = x + (size_t)(t0 + q) * DIN;
      for (int d = lane; d < DIN; d += 64) {
        float xv = xr[d];
        const float4* wp = (const float4*)(wrow + (size_t)d * RANK);
        float4 w0 = wp[0], w1 = wp[1], w2 = wp[2], w3 = wp[3];
        float wv[16] = {w0.x, w0.y, w0.z, w0.w, w1.x, w1.y, w1.z, w1.w,
                        w2.x, w2.y, w2.z, w2.w, w3.x, w3.y, w3.z, w3.w};
#pragma unroll
        for (int r = 0; r < 16; ++r) acc[q][r] += xv * wv[r];
      }
    }
  }

#pragma unroll
  for (int q = 0; q < 4; ++q) {
#pragma unroll
    for (int r = 0; r < 16; ++r) {
      float v = acc[q][r];
      v += __shfl_xor(v, 1);
      v += __shfl_xor(v, 2);
      v += __shfl_xor(v, 4);
      v += __shfl_xor(v, 8);
      v += __shfl_xor(v, 16);
      v += __shfl_xor(v, 32);
      acc[q][r] = v;
    }
    if (lane == 0) {
      int t = t0 + q;
      tokid[t] = ids[q];
#pragma unroll
      for (int r = 0; r < 16; ++r) hbuf[t * RANK + r] = sc[q] * acc[q][r];
    }
  }
}

// ------------------------------------------------------------- main fused GEMM
// C[t,o] = sum_k x[t,k]*w[o,k]  (both bf16, K-major) + bias[o]
//        + sum_r h'[t,r]*wb[id_t,r,o]
// 128x128 tile, BK=64, 4 waves (2x2 of 64x64), mfma_f32_16x16x32_bf16.
__global__ __launch_bounds__(256) void gemm_fused(const unsigned short* __restrict__ A,
                                                  const unsigned short* __restrict__ B,
                                                  const float* __restrict__ bias,
                                                  const float* __restrict__ hbuf,
                                                  const int* __restrict__ tokid,
                                                  const float* __restrict__ wbt,
                                                  float* __restrict__ out) {
  __shared__ unsigned short As[128 * 64];
  __shared__ unsigned short Bs[128 * 64];

  const int tid = threadIdx.x;
  const int lane = tid & 63;
  const int wave = tid >> 6;
  const int wr = wave >> 1;
  const int wc = wave & 1;
  const int brow = blockIdx.y * 128;
  const int bcol = blockIdx.x * 128;

  f32x4 acc[4][4] = {};

  const int ldr = lane >> 3;        // sub-row within 8-row chunk
  const int ldc = (lane & 7) * 8;   // k-element offset (8 bf16 = 16B)
  const int rsel = lane & 15;       // fragment row/col select
  const int khalf = (lane >> 4) * 8;

  for (int kt = 0; kt < DIN; kt += 64) {
    // ---- stage A,B tiles (16 KB each) via direct global->LDS, 16B/lane
#pragma unroll
    for (int i = 0; i < 4; ++i) {
      const int ii = wave * 4 + i;      // 16 chunks of 1KB per tile
      const int row = ii * 8 + ldr;     // 0..127
      const unsigned short* gA = A + (size_t)(brow + row) * DIN + kt + ldc;
      const unsigned short* gB = B + (size_t)(bcol + row) * DIN + kt + ldc;
      __builtin_amdgcn_global_load_lds(GLB_PTR(gA), LDS_PTR(As + ii * 512 + lane * 8), 16, 0, 0);
      __builtin_amdgcn_global_load_lds(GLB_PTR(gB), LDS_PTR(Bs + ii * 512 + lane * 8), 16, 0, 0);
    }
    __syncthreads();
    // ---- compute 2 K-slices of 32
#pragma unroll
    for (int ks = 0; ks < 2; ++ks) {
      bf16x8 a[4], b[4];
      const int ko = ks * 32 + khalf;
#pragma unroll
      for (int m = 0; m < 4; ++m)
        a[m] = *(const bf16x8*)(As + (wr * 64 + m * 16 + rsel) * 64 + ko);
#pragma unroll
      for (int n = 0; n < 4; ++n)
        b[n] = *(const bf16x8*)(Bs + (wc * 64 + n * 16 + rsel) * 64 + ko);
#pragma unroll
      for (int m = 0; m < 4; ++m)
#pragma unroll
        for (int n = 0; n < 4; ++n)
          acc[m][n] = __builtin_amdgcn_mfma_f32_16x16x32_bf16(a[m], b[n], acc[m][n], 0, 0, 0);
    }
    __syncthreads();
  }

  // ---- epilogue: bias + rank-16 LoRA + store
  const int rb = brow + wr * 64;
  const int cb = bcol + wc * 64;
  const int crow = (lane >> 4) * 4;
  const int ccol = lane & 15;

  float biasn[4];
#pragma unroll
  for (int n = 0; n < 4; ++n) biasn[n] = bias[cb + n * 16 + ccol];

#pragma unroll
  for (int m = 0; m < 4; ++m) {
#pragma unroll
    for (int j = 0; j < 4; ++j) {
      const int row = rb + m * 16 + crow + j;
      const float4* hp = (const float4*)(hbuf + (size_t)row * RANK);
      float4 h0 = hp[0], h1 = hp[1], h2 = hp[2], h3 = hp[3];
      float hv[16] = {h0.x, h0.y, h0.z, h0.w, h1.x, h1.y, h1.z, h1.w,
                      h2.x, h2.y, h2.z, h2.w, h3.x, h3.y, h3.z, h3.w};
      const float* wrow = wbt + (size_t)tokid[row] * RANK * DOUTF;
      float* orow = out + (size_t)row * DOUTF;
#pragma unroll
      for (int n = 0; n < 4; ++n) {
        const int col = cb + n * 16 + ccol;
        float v = acc[m][n][j] + biasn[n];
#pragma unroll
        for (int r = 0; r < 16; ++r) v += hv[r] * wrow[(size_t)r * DOUTF + col];
        orow[col] = v;
      }
    }
  }
}

// ---------------------------------------------------------------------- launch
extern "C" void kernel_launch(void* const* d_in, const int* in_sizes, int n_in,
                              void* d_out, int out_size, void* d_ws, size_t ws_size,
                              hipStream_t stream) {
  const float* x       = (const float*)d_in[0];
  const float* base_w  = (const float*)d_in[1];
  const float* base_b  = (const float*)d_in[2];
  const float* wa      = (const float*)d_in[3];
  const float* wb      = (const float*)d_in[4];
  const float* scaling = (const float*)d_in[5];
  const int*   segment = (const int*)d_in[6];
  const int*   lora_id = (const int*)d_in[7];
  float* out = (float*)d_out;

  char* ws = (char*)d_ws;
  unsigned short* xb  = (unsigned short*)ws;                                   // 64 MB
  unsigned short* wbf = (unsigned short*)(ws + (size_t)T_TOK * DIN * 2);       // 32 MB
  float* hbuf = (float*)(ws + (size_t)T_TOK * DIN * 2 + (size_t)DOUTF * DIN * 2);
  int* tokid  = (int*)((char*)hbuf + (size_t)T_TOK * RANK * 4);

  cvt_f32_bf16<<<2048, 256, 0, stream>>>(x, xb, (T_TOK * DIN) / 8);
  cvt_f32_bf16<<<2048, 256, 0, stream>>>(base_w, wbf, (DOUTF * DIN) / 8);
  lora_h<<<T_TOK / 16, 256, 0, stream>>>(x, wa, scaling, segment, lora_id, hbuf, tokid);
  gemm_fused<<<dim3(DOUTF / 128, T_TOK / 128), 256, 0, stream>>>(xb, wbf, base_b, hbuf,
                                                                 tokid, wb, out);
}

// Round 2
// 801.972 us; speedup vs baseline: 1.2662x; 1.2662x over previous
//
#include <hip/hip_runtime.h>

#define T_TOK 8192
#define DIN   4096
#define DOUTF 4096
#define RANK  16
#define NADP  8

typedef __attribute__((ext_vector_type(4))) float f32x4;
typedef __attribute__((ext_vector_type(8))) short bf16x8;
typedef __attribute__((ext_vector_type(8))) unsigned short u16x8;

#define GLB_PTR(p) ((const __attribute__((address_space(1))) void*)(p))
#define LDS_PTR(p) ((__attribute__((address_space(3))) void*)(p))

__device__ __forceinline__ unsigned short f2bf(float f) {
  unsigned u = __float_as_uint(f);
  u = (u + 0x7fffu + ((u >> 16) & 1u)) >> 16;  // RNE
  return (unsigned short)u;
}

// ---------------------------------------------------------------- fp32 -> bf16
__global__ __launch_bounds__(256) void cvt_f32_bf16(const float* __restrict__ in,
                                                    unsigned short* __restrict__ out,
                                                    int n8) {
  const int stride = gridDim.x * blockDim.x;
  for (int i = blockIdx.x * blockDim.x + threadIdx.x; i < n8; i += stride) {
    const float4* p = (const float4*)(in + (size_t)i * 8);
    float4 a = p[0], b = p[1];
    u16x8 r;
    r[0] = f2bf(a.x); r[1] = f2bf(a.y); r[2] = f2bf(a.z); r[3] = f2bf(a.w);
    r[4] = f2bf(b.x); r[5] = f2bf(b.y); r[6] = f2bf(b.z); r[7] = f2bf(b.w);
    *(u16x8*)(out + (size_t)i * 8) = r;
  }
}

// ----------------- h'[t,r] = scaling * x @ wa[id_t]; also emits x in bf16 -----
// block = 256 threads = 4 waves; each wave handles 4 consecutive tokens.
__global__ __launch_bounds__(256) void lora_h(const float* __restrict__ x,
                                              const float* __restrict__ wa,
                                              const float* __restrict__ scaling,
                                              const int* __restrict__ segment,
                                              const int* __restrict__ lora_ids,
                                              float* __restrict__ hbuf,
                                              int* __restrict__ tokid,
                                              unsigned short* __restrict__ xb) {
  const int lane = threadIdx.x & 63;
  const int wave = threadIdx.x >> 6;
  const int t0 = blockIdx.x * 16 + wave * 4;

  int ids[4]; float sc[4];
#pragma unroll
  for (int q = 0; q < 4; ++q) {
    int t = t0 + q;
    int s = 0;
#pragma unroll
    for (int i = 1; i < 8; ++i)
      if (t >= segment[i]) s = i;
    int id = lora_ids[s];
    ids[q] = id;
    sc[q] = scaling[id];
  }

  float acc[4][16];
#pragma unroll
  for (int q = 0; q < 4; ++q)
#pragma unroll
    for (int r = 0; r < 16; ++r) acc[q][r] = 0.f;

  const bool same = (ids[0] == ids[1]) && (ids[1] == ids[2]) && (ids[2] == ids[3]);
  if (same) {
    const float* wrow = wa + (size_t)ids[0] * DIN * RANK;
    const float* xr0 = x + (size_t)(t0 + 0) * DIN;
    const float* xr1 = x + (size_t)(t0 + 1) * DIN;
    const float* xr2 = x + (size_t)(t0 + 2) * DIN;
    const float* xr3 = x + (size_t)(t0 + 3) * DIN;
    for (int d = lane; d < DIN; d += 64) {
      float xv[4] = {xr0[d], xr1[d], xr2[d], xr3[d]};
#pragma unroll
      for (int q = 0; q < 4; ++q) xb[(size_t)(t0 + q) * DIN + d] = f2bf(xv[q]);
      const float4* wp = (const float4*)(wrow + (size_t)d * RANK);
      float4 w0 = wp[0], w1 = wp[1], w2 = wp[2], w3 = wp[3];
      float wv[16] = {w0.x, w0.y, w0.z, w0.w, w1.x, w1.y, w1.z, w1.w,
                      w2.x, w2.y, w2.z, w2.w, w3.x, w3.y, w3.z, w3.w};
#pragma unroll
      for (int q = 0; q < 4; ++q)
#pragma unroll
        for (int r = 0; r < 16; ++r) acc[q][r] += xv[q] * wv[r];
    }
  } else {
#pragma unroll
    for (int q = 0; q < 4; ++q) {
      const float* wrow = wa + (size_t)ids[q] * DIN * RANK;
      const float* xr = x + (size_t)(t0 + q) * DIN;
      for (int d = lane; d < DIN; d += 64) {
        float xv = xr[d];
        xb[(size_t)(t0 + q) * DIN + d] = f2bf(xv);
        const float4* wp = (const float4*)(wrow + (size_t)d * RANK);
        float4 w0 = wp[0], w1 = wp[1], w2 = wp[2], w3 = wp[3];
        float wv[16] = {w0.x, w0.y, w0.z, w0.w, w1.x, w1.y, w1.z, w1.w,
                        w2.x, w2.y, w2.z, w2.w, w3.x, w3.y, w3.z, w3.w};
#pragma unroll
        for (int r = 0; r < 16; ++r) acc[q][r] += xv * wv[r];
      }
    }
  }

#pragma unroll
  for (int q = 0; q < 4; ++q) {
#pragma unroll
    for (int r = 0; r < 16; ++r) {
      float v = acc[q][r];
      v += __shfl_xor(v, 1);
      v += __shfl_xor(v, 2);
      v += __shfl_xor(v, 4);
      v += __shfl_xor(v, 8);
      v += __shfl_xor(v, 16);
      v += __shfl_xor(v, 32);
      acc[q][r] = v;
    }
    if (lane == 0) {
      int t = t0 + q;
      tokid[t] = ids[q];
#pragma unroll
      for (int r = 0; r < 16; ++r) hbuf[t * RANK + r] = sc[q] * acc[q][r];
    }
  }
}

// ------------------------------------------------------------- main fused GEMM
// C[t,o] = sum_k x[t,k]*w[o,k]  (both bf16, K-major) + bias[o]
//        + sum_r h'[t,r]*wb[id_t,r,o]
// 128x128 tile, BK=64, 4 waves (2x2 of 64x64), mfma_f32_16x16x32_bf16.
//
// LDS tile is [128 rows][64 bf16] = 128 B/row == 32 banks -> the naive read
// (16 lanes, 16 rows, same chunk) is a 16-way conflict. Fix (rule #21,
// both-sides-or-neither): keep global_load_lds dest LINEAR, XOR-permute the
// 16B chunk on the global SOURCE address, and apply the same XOR on the
// ds_read address. LDS[r][p] holds logical chunk p^(r&7).
__global__ __launch_bounds__(256) void gemm_fused(const unsigned short* __restrict__ A,
                                                  const unsigned short* __restrict__ B,
                                                  const float* __restrict__ bias,
                                                  const float* __restrict__ hbuf,
                                                  const int* __restrict__ tokid,
                                                  const float* __restrict__ wbt,
                                                  float* __restrict__ out) {
  __shared__ unsigned short As[128 * 64];
  __shared__ unsigned short Bs[128 * 64];

  const int tid = threadIdx.x;
  const int lane = tid & 63;
  const int wave = tid >> 6;
  const int wr = wave >> 1;
  const int wc = wave & 1;
  const int brow = blockIdx.y * 128;
  const int bcol = blockIdx.x * 128;

  f32x4 acc[4][4] = {};

  const int ldr = lane >> 3;                         // sub-row within 8-row chunk
  const int ldc = ((lane & 7) ^ (lane >> 3)) * 8;    // SWIZZLED source chunk
  const int rsel = lane & 15;                        // fragment row select
  const int lo3 = lane & 7;

  for (int kt = 0; kt < DIN; kt += 64) {
    // ---- stage A,B tiles (16 KB each) via direct global->LDS, 16B/lane
#pragma unroll
    for (int i = 0; i < 4; ++i) {
      const int ii = wave * 4 + i;      // 16 chunks of 1KB per tile
      const int row = ii * 8 + ldr;     // 0..127
      const unsigned short* gA = A + (size_t)(brow + row) * DIN + kt + ldc;
      const unsigned short* gB = B + (size_t)(bcol + row) * DIN + kt + ldc;
      __builtin_amdgcn_global_load_lds(GLB_PTR(gA), LDS_PTR(As + ii * 512 + lane * 8), 16, 0, 0);
      __builtin_amdgcn_global_load_lds(GLB_PTR(gB), LDS_PTR(Bs + ii * 512 + lane * 8), 16, 0, 0);
    }
    __syncthreads();
    // ---- compute 2 K-slices of 32
#pragma unroll
    for (int ks = 0; ks < 2; ++ks) {
      bf16x8 a[4], b[4];
      // logical 16B chunk = ks*4 + (lane>>4); physical = logical ^ (row&7),
      // and row&7 == rsel&7 == lo3's owner row bits (m*16, w*64 are 0 mod 8)
      const int phys = ((ks * 4 + (lane >> 4)) ^ lo3) * 8;
#pragma unroll
      for (int m = 0; m < 4; ++m)
        a[m] = *(const bf16x8*)(As + (wr * 64 + m * 16 + rsel) * 64 + phys);
#pragma unroll
      for (int n = 0; n < 4; ++n)
        b[n] = *(const bf16x8*)(Bs + (wc * 64 + n * 16 + rsel) * 64 + phys);
#pragma unroll
      for (int m = 0; m < 4; ++m)
#pragma unroll
        for (int n = 0; n < 4; ++n)
          acc[m][n] = __builtin_amdgcn_mfma_f32_16x16x32_bf16(a[m], b[n], acc[m][n], 0, 0, 0);
    }
    __syncthreads();
  }

  // ---- epilogue: bias + rank-16 LoRA + store
  const int rb = brow + wr * 64;
  const int cb = bcol + wc * 64;
  const int crow = (lane >> 4) * 4;
  const int ccol = lane & 15;

  float biasn[4];
#pragma unroll
  for (int n = 0; n < 4; ++n) biasn[n] = bias[cb + n * 16 + ccol];

#pragma unroll
  for (int m = 0; m < 4; ++m) {
#pragma unroll
    for (int j = 0; j < 4; ++j) {
      const int row = rb + m * 16 + crow + j;
      const float4* hp = (const float4*)(hbuf + (size_t)row * RANK);
      float4 h0 = hp[0], h1 = hp[1], h2 = hp[2], h3 = hp[3];
      float hv[16] = {h0.x, h0.y, h0.z, h0.w, h1.x, h1.y, h1.z, h1.w,
                      h2.x, h2.y, h2.z, h2.w, h3.x, h3.y, h3.z, h3.w};
      const float* wrow = wbt + (size_t)tokid[row] * RANK * DOUTF;
      float* orow = out + (size_t)row * DOUTF;
#pragma unroll
      for (int n = 0; n < 4; ++n) {
        const int col = cb + n * 16 + ccol;
        float v = acc[m][n][j] + biasn[n];
#pragma unroll
        for (int r = 0; r < 16; ++r) v += hv[r] * wrow[(size_t)r * DOUTF + col];
        orow[col] = v;
      }
    }
  }
}

// ---------------------------------------------------------------------- launch
extern "C" void kernel_launch(void* const* d_in, const int* in_sizes, int n_in,
                              void* d_out, int out_size, void* d_ws, size_t ws_size,
                              hipStream_t stream) {
  const float* x       = (const float*)d_in[0];
  const float* base_w  = (const float*)d_in[1];
  const float* base_b  = (const float*)d_in[2];
  const float* wa      = (const float*)d_in[3];
  const float* wb      = (const float*)d_in[4];
  const float* scaling = (const float*)d_in[5];
  const int*   segment = (const int*)d_in[6];
  const int*   lora_id = (const int*)d_in[7];
  float* out = (float*)d_out;

  char* ws = (char*)d_ws;
  unsigned short* xb  = (unsigned short*)ws;                                   // 64 MB
  unsigned short* wbf = (unsigned short*)(ws + (size_t)T_TOK * DIN * 2);       // 32 MB
  float* hbuf = (float*)(ws + (size_t)T_TOK * DIN * 2 + (size_t)DOUTF * DIN * 2);
  int* tokid  = (int*)((char*)hbuf + (size_t)T_TOK * RANK * 4);

  cvt_f32_bf16<<<2048, 256, 0, stream>>>(base_w, wbf, (DOUTF * DIN) / 8);
  lora_h<<<T_TOK / 16, 256, 0, stream>>>(x, wa, scaling, segment, lora_id, hbuf, tokid, xb);
  gemm_fused<<<dim3(DOUTF / 128, T_TOK / 128), 256, 0, stream>>>(xb, wbf, base_b, hbuf,
                                                                 tokid, wb, out);
}

// Round 3
// 517.706 us; speedup vs baseline: 1.9615x; 1.5491x over previous
//
#include <hip/hip_runtime.h>

#define T_TOK 8192
#define DIN   4096
#define DOUTF 4096
#define RANK  16

#define BM 256
#define BN 256
#define BK 64
#define NT (DIN / BK)  // 64 K-tiles

typedef __attribute__((ext_vector_type(4))) float f32x4;
typedef __attribute__((ext_vector_type(8))) short bf16x8;
typedef __attribute__((ext_vector_type(8))) unsigned short u16x8;

#define GLB_PTR(p) ((const __attribute__((address_space(1))) void*)(p))
#define LDS_PTR(p) ((__attribute__((address_space(3))) void*)(p))

__device__ __forceinline__ unsigned short f2bf(float f) {
  unsigned u = __float_as_uint(f);
  u = (u + 0x7fffu + ((u >> 16) & 1u)) >> 16;  // RNE
  return (unsigned short)u;
}

// ---------------------------------------------------------------- fp32 -> bf16
__global__ __launch_bounds__(256) void cvt_f32_bf16(const float* __restrict__ in,
                                                    unsigned short* __restrict__ out,
                                                    int n8) {
  const int stride = gridDim.x * blockDim.x;
  for (int i = blockIdx.x * blockDim.x + threadIdx.x; i < n8; i += stride) {
    const float4* p = (const float4*)(in + (size_t)i * 8);
    float4 a = p[0], b = p[1];
    u16x8 r;
    r[0] = f2bf(a.x); r[1] = f2bf(a.y); r[2] = f2bf(a.z); r[3] = f2bf(a.w);
    r[4] = f2bf(b.x); r[5] = f2bf(b.y); r[6] = f2bf(b.z); r[7] = f2bf(b.w);
    *(u16x8*)(out + (size_t)i * 8) = r;
  }
}

// ----------------- h'[t,r] = scaling * x @ wa[id_t]; also emits x in bf16 -----
__global__ __launch_bounds__(256) void lora_h(const float* __restrict__ x,
                                              const float* __restrict__ wa,
                                              const float* __restrict__ scaling,
                                              const int* __restrict__ segment,
                                              const int* __restrict__ lora_ids,
                                              float* __restrict__ hbuf,
                                              int* __restrict__ tokid,
                                              unsigned short* __restrict__ xb) {
  const int lane = threadIdx.x & 63;
  const int wave = threadIdx.x >> 6;
  const int t0 = blockIdx.x * 16 + wave * 4;

  int ids[4]; float sc[4];
#pragma unroll
  for (int q = 0; q < 4; ++q) {
    int t = t0 + q;
    int s = 0;
#pragma unroll
    for (int i = 1; i < 8; ++i)
      if (t >= segment[i]) s = i;
    int id = lora_ids[s];
    ids[q] = id;
    sc[q] = scaling[id];
  }

  float acc[4][16];
#pragma unroll
  for (int q = 0; q < 4; ++q)
#pragma unroll
    for (int r = 0; r < 16; ++r) acc[q][r] = 0.f;

  const bool same = (ids[0] == ids[1]) && (ids[1] == ids[2]) && (ids[2] == ids[3]);
  if (same) {
    const float* wrow = wa + (size_t)ids[0] * DIN * RANK;
    const float* xr0 = x + (size_t)(t0 + 0) * DIN;
    const float* xr1 = x + (size_t)(t0 + 1) * DIN;
    const float* xr2 = x + (size_t)(t0 + 2) * DIN;
    const float* xr3 = x + (size_t)(t0 + 3) * DIN;
    for (int d = lane; d < DIN; d += 64) {
      float xv[4] = {xr0[d], xr1[d], xr2[d], xr3[d]};
#pragma unroll
      for (int q = 0; q < 4; ++q) xb[(size_t)(t0 + q) * DIN + d] = f2bf(xv[q]);
      const float4* wp = (const float4*)(wrow + (size_t)d * RANK);
      float4 w0 = wp[0], w1 = wp[1], w2 = wp[2], w3 = wp[3];
      float wv[16] = {w0.x, w0.y, w0.z, w0.w, w1.x, w1.y, w1.z, w1.w,
                      w2.x, w2.y, w2.z, w2.w, w3.x, w3.y, w3.z, w3.w};
#pragma unroll
      for (int q = 0; q < 4; ++q)
#pragma unroll
        for (int r = 0; r < 16; ++r) acc[q][r] += xv[q] * wv[r];
    }
  } else {
#pragma unroll
    for (int q = 0; q < 4; ++q) {
      const float* wrow = wa + (size_t)ids[q] * DIN * RANK;
      const float* xr = x + (size_t)(t0 + q) * DIN;
      for (int d = lane; d < DIN; d += 64) {
        float xv = xr[d];
        xb[(size_t)(t0 + q) * DIN + d] = f2bf(xv);
        const float4* wp = (const float4*)(wrow + (size_t)d * RANK);
        float4 w0 = wp[0], w1 = wp[1], w2 = wp[2], w3 = wp[3];
        float wv[16] = {w0.x, w0.y, w0.z, w0.w, w1.x, w1.y, w1.z, w1.w,
                        w2.x, w2.y, w2.z, w2.w, w3.x, w3.y, w3.z, w3.w};
#pragma unroll
        for (int r = 0; r < 16; ++r) acc[q][r] += xv * wv[r];
      }
    }
  }

#pragma unroll
  for (int q = 0; q < 4; ++q) {
#pragma unroll
    for (int r = 0; r < 16; ++r) {
      float v = acc[q][r];
      v += __shfl_xor(v, 1);
      v += __shfl_xor(v, 2);
      v += __shfl_xor(v, 4);
      v += __shfl_xor(v, 8);
      v += __shfl_xor(v, 16);
      v += __shfl_xor(v, 32);
      acc[q][r] = v;
    }
    if (lane == 0) {
      int t = t0 + q;
      tokid[t] = ids[q];
#pragma unroll
      for (int r = 0; r < 16; ++r) hbuf[t * RANK + r] = sc[q] * acc[q][r];
    }
  }
}

// ------------------------------------------------------------- main fused GEMM
// 256x256 tile, BK=64, 8 waves (2M x 4N), per-wave output 128x64.
// Double-buffered 128 KB LDS; all 8 stage insts for tile t+1 front-loaded at
// the top of tile t's compute (~4 phases of slack covers L2/L3 latency, so the
// boundary __syncthreads vmcnt(0) drain is nearly free). 4 phases per K-tile:
// {ds_read a-pair -> raw s_barrier -> setprio(1) 16 MFMA setprio(0) -> raw
// s_barrier}. b-frags read once per K-tile and cached (keeps LDS read traffic
// at 192 KB/CU/K-tile, below the 2483-cy MFMA floor). XOR-chunk swizzle on
// both staging source and ds_read (round-2-proven: 0 bank conflicts).
__global__ __launch_bounds__(512, 2) void gemm_fused(const unsigned short* __restrict__ A,
                                                     const unsigned short* __restrict__ B,
                                                     const float* __restrict__ bias,
                                                     const float* __restrict__ hbuf,
                                                     const int* __restrict__ tokid,
                                                     const float* __restrict__ wbt,
                                                     float* __restrict__ out) {
  __shared__ __align__(16) unsigned short As[2][BM * BK];  // 2 x 32 KB
  __shared__ __align__(16) unsigned short Bs[2][BN * BK];  // 2 x 32 KB

  const int tid = threadIdx.x;
  const int lane = tid & 63;
  const int wave = tid >> 6;   // 0..7
  const int wr = wave >> 2;    // 0..1  M half
  const int wn = wave & 3;     // 0..3  N quarter

  // XCD-aware bijective swizzle: 512 blocks, 64-block chunk per XCD
  const int bsw = (blockIdx.x & 7) * 64 + (blockIdx.x >> 3);
  const int brow = (bsw >> 4) * BM;   // 32 M-blocks
  const int bcol = (bsw & 15) * BN;   // 16 N-blocks

  f32x4 acc[8][4] = {};

  const int s_sub = lane >> 3;                             // staging sub-row
  const int s_src = ((lane & 7) ^ (lane >> 3)) * 8;        // swizzled src k-off
  const int rsel = lane & 15;

#define STAGE(p, kt)                                                                   \
  {                                                                                    \
    _Pragma("unroll")                                                                  \
    for (int i = 0; i < 4; ++i) {                                                      \
      const int r = i * 64 + wave * 8 + s_sub;                                         \
      const unsigned short* gA = A + (size_t)(brow + r) * DIN + (kt) + s_src;          \
      const unsigned short* gB = B + (size_t)(bcol + r) * DIN + (kt) + s_src;          \
      __builtin_amdgcn_global_load_lds(GLB_PTR(gA), LDS_PTR(&As[p][(i * 512 + tid) * 8]), 16, 0, 0); \
      __builtin_amdgcn_global_load_lds(GLB_PTR(gB), LDS_PTR(&Bs[p][(i * 512 + tid) * 8]), 16, 0, 0); \
    }                                                                                  \
  }

  STAGE(0, 0);
  __syncthreads();

  for (int t = 0; t < NT; ++t) {
    const int p = t & 1;
    if (t + 1 < NT) STAGE(p ^ 1, (t + 1) * BK);  // front-loaded prefetch

    const unsigned short* Asp = As[p];
    const unsigned short* Bsp = Bs[p];

    // b-frags: read once per K-tile, cached across the 4 phases (32 VGPR)
    bf16x8 bfr[4][2];
#pragma unroll
    for (int kk = 0; kk < 2; ++kk) {
      const int phys = ((kk * 4 + (lane >> 4)) ^ (lane & 7)) * 8;
#pragma unroll
      for (int n = 0; n < 4; ++n)
        bfr[n][kk] = *(const bf16x8*)(Bsp + (wn * 64 + n * 16 + rsel) * BK + phys);
    }

#pragma unroll
    for (int ph = 0; ph < 4; ++ph) {
      bf16x8 afr[2][2];
#pragma unroll
      for (int kk = 0; kk < 2; ++kk) {
        const int phys = ((kk * 4 + (lane >> 4)) ^ (lane & 7)) * 8;
#pragma unroll
        for (int mi = 0; mi < 2; ++mi)
          afr[mi][kk] = *(const bf16x8*)(Asp + (wr * 128 + (ph * 2 + mi) * 16 + rsel) * BK + phys);
      }
      __builtin_amdgcn_s_barrier();       // scheduling barrier (no drain)
      __builtin_amdgcn_s_setprio(1);
#pragma unroll
      for (int kk = 0; kk < 2; ++kk)
#pragma unroll
        for (int mi = 0; mi < 2; ++mi)
#pragma unroll
          for (int n = 0; n < 4; ++n)
            acc[ph * 2 + mi][n] = __builtin_amdgcn_mfma_f32_16x16x32_bf16(
                afr[mi][kk], bfr[n][kk], acc[ph * 2 + mi][n], 0, 0, 0);
      __builtin_amdgcn_s_setprio(0);
      __builtin_amdgcn_s_barrier();
    }
    __syncthreads();  // vmcnt(0)+lgkmcnt(0) drain + buffer swap (loads have ~4 phases slack)
  }

  // ---- epilogue: bias + rank-16 LoRA + store
  const int rb = brow + wr * 128;
  const int cb = bcol + wn * 64;
  const int crow = (lane >> 4) * 4;
  const int ccol = lane & 15;

  float biasn[4];
#pragma unroll
  for (int n = 0; n < 4; ++n) biasn[n] = bias[cb + n * 16 + ccol];

#pragma unroll
  for (int m = 0; m < 8; ++m) {
#pragma unroll
    for (int j = 0; j < 4; ++j) {
      const int row = rb + m * 16 + crow + j;
      const float4* hp = (const float4*)(hbuf + (size_t)row * RANK);
      float4 h0 = hp[0], h1 = hp[1], h2 = hp[2], h3 = hp[3];
      float hv[16] = {h0.x, h0.y, h0.z, h0.w, h1.x, h1.y, h1.z, h1.w,
                      h2.x, h2.y, h2.z, h2.w, h3.x, h3.y, h3.z, h3.w};
      const float* wrow = wbt + (size_t)tokid[row] * RANK * DOUTF;
      float* orow = out + (size_t)row * DOUTF;
#pragma unroll
      for (int n = 0; n < 4; ++n) {
        const int col = cb + n * 16 + ccol;
        float v = acc[m][n][j] + biasn[n];
#pragma unroll
        for (int r = 0; r < 16; ++r) v += hv[r] * wrow[(size_t)r * DOUTF + col];
        orow[col] = v;
      }
    }
  }
#undef STAGE
}

// ---------------------------------------------------------------------- launch
extern "C" void kernel_launch(void* const* d_in, const int* in_sizes, int n_in,
                              void* d_out, int out_size, void* d_ws, size_t ws_size,
                              hipStream_t stream) {
  const float* x       = (const float*)d_in[0];
  const float* base_w  = (const float*)d_in[1];
  const float* base_b  = (const float*)d_in[2];
  const float* wa      = (const float*)d_in[3];
  const float* wb      = (const float*)d_in[4];
  const float* scaling = (const float*)d_in[5];
  const int*   segment = (const int*)d_in[6];
  const int*   lora_id = (const int*)d_in[7];
  float* out = (float*)d_out;

  char* ws = (char*)d_ws;
  unsigned short* xb  = (unsigned short*)ws;                                   // 64 MB
  unsigned short* wbf = (unsigned short*)(ws + (size_t)T_TOK * DIN * 2);       // 32 MB
  float* hbuf = (float*)(ws + (size_t)T_TOK * DIN * 2 + (size_t)DOUTF * DIN * 2);
  int* tokid  = (int*)((char*)hbuf + (size_t)T_TOK * RANK * 4);

  cvt_f32_bf16<<<2048, 256, 0, stream>>>(base_w, wbf, (DOUTF * DIN) / 8);
  lora_h<<<T_TOK / 16, 256, 0, stream>>>(x, wa, scaling, segment, lora_id, hbuf, tokid, xb);
  gemm_fused<<<(T_TOK / BM) * (DOUTF / BN), 512, 0, stream>>>(xb, wbf, base_b, hbuf,
                                                              tokid, wb, out);
}

// Round 4
// 516.753 us; speedup vs baseline: 1.9651x; 1.0018x over previous
//
#include <hip/hip_runtime.h>

#define T_TOK 8192
#define DIN   4096
#define DOUTF 4096
#define RANK  16

#define BM 256
#define BN 256
#define BK 32
#define NT (DIN / BK)  // 128 K-tiles

typedef __attribute__((ext_vector_type(4))) float f32x4;
typedef __attribute__((ext_vector_type(8))) short bf16x8;
typedef __attribute__((ext_vector_type(8))) unsigned short u16x8;

#define GLB_PTR(p) ((const __attribute__((address_space(1))) void*)(p))
#define LDS_PTR(p) ((__attribute__((address_space(3))) void*)(p))

__device__ __forceinline__ unsigned short f2bf(float f) {
  unsigned u = __float_as_uint(f);
  u = (u + 0x7fffu + ((u >> 16) & 1u)) >> 16;  // RNE
  return (unsigned short)u;
}

// ---------------------------------------------------------------- fp32 -> bf16
__global__ __launch_bounds__(256) void cvt_f32_bf16(const float* __restrict__ in,
                                                    unsigned short* __restrict__ out,
                                                    int n8) {
  const int stride = gridDim.x * blockDim.x;
  for (int i = blockIdx.x * blockDim.x + threadIdx.x; i < n8; i += stride) {
    const float4* p = (const float4*)(in + (size_t)i * 8);
    float4 a = p[0], b = p[1];
    u16x8 r;
    r[0] = f2bf(a.x); r[1] = f2bf(a.y); r[2] = f2bf(a.z); r[3] = f2bf(a.w);
    r[4] = f2bf(b.x); r[5] = f2bf(b.y); r[6] = f2bf(b.z); r[7] = f2bf(b.w);
    *(u16x8*)(out + (size_t)i * 8) = r;
  }
}

// ----------------- h'[t,r] = scaling * x @ wa[id_t]; emits x bf16 + h' bf16 ---
__global__ __launch_bounds__(256) void lora_h(const float* __restrict__ x,
                                              const float* __restrict__ wa,
                                              const float* __restrict__ scaling,
                                              const int* __restrict__ segment,
                                              const int* __restrict__ lora_ids,
                                              float* __restrict__ hbuf,
                                              unsigned short* __restrict__ hb16,
                                              int* __restrict__ tokid,
                                              unsigned short* __restrict__ xb) {
  const int lane = threadIdx.x & 63;
  const int wave = threadIdx.x >> 6;
  const int t0 = blockIdx.x * 16 + wave * 4;

  int ids[4]; float sc[4];
#pragma unroll
  for (int q = 0; q < 4; ++q) {
    int t = t0 + q;
    int s = 0;
#pragma unroll
    for (int i = 1; i < 8; ++i)
      if (t >= segment[i]) s = i;
    int id = lora_ids[s];
    ids[q] = id;
    sc[q] = scaling[id];
  }

  float acc[4][16];
#pragma unroll
  for (int q = 0; q < 4; ++q)
#pragma unroll
    for (int r = 0; r < 16; ++r) acc[q][r] = 0.f;

  const bool same = (ids[0] == ids[1]) && (ids[1] == ids[2]) && (ids[2] == ids[3]);
  if (same) {
    const float* wrow = wa + (size_t)ids[0] * DIN * RANK;
    const float* xr0 = x + (size_t)(t0 + 0) * DIN;
    const float* xr1 = x + (size_t)(t0 + 1) * DIN;
    const float* xr2 = x + (size_t)(t0 + 2) * DIN;
    const float* xr3 = x + (size_t)(t0 + 3) * DIN;
    for (int d = lane; d < DIN; d += 64) {
      float xv[4] = {xr0[d], xr1[d], xr2[d], xr3[d]};
#pragma unroll
      for (int q = 0; q < 4; ++q) xb[(size_t)(t0 + q) * DIN + d] = f2bf(xv[q]);
      const float4* wp = (const float4*)(wrow + (size_t)d * RANK);
      float4 w0 = wp[0], w1 = wp[1], w2 = wp[2], w3 = wp[3];
      float wv[16] = {w0.x, w0.y, w0.z, w0.w, w1.x, w1.y, w1.z, w1.w,
                      w2.x, w2.y, w2.z, w2.w, w3.x, w3.y, w3.z, w3.w};
#pragma unroll
      for (int q = 0; q < 4; ++q)
#pragma unroll
        for (int r = 0; r < 16; ++r) acc[q][r] += xv[q] * wv[r];
    }
  } else {
#pragma unroll
    for (int q = 0; q < 4; ++q) {
      const float* wrow = wa + (size_t)ids[q] * DIN * RANK;
      const float* xr = x + (size_t)(t0 + q) * DIN;
      for (int d = lane; d < DIN; d += 64) {
        float xv = xr[d];
        xb[(size_t)(t0 + q) * DIN + d] = f2bf(xv);
        const float4* wp = (const float4*)(wrow + (size_t)d * RANK);
        float4 w0 = wp[0], w1 = wp[1], w2 = wp[2], w3 = wp[3];
        float wv[16] = {w0.x, w0.y, w0.z, w0.w, w1.x, w1.y, w1.z, w1.w,
                        w2.x, w2.y, w2.z, w2.w, w3.x, w3.y, w3.z, w3.w};
#pragma unroll
        for (int r = 0; r < 16; ++r) acc[q][r] += xv * wv[r];
      }
    }
  }

#pragma unroll
  for (int q = 0; q < 4; ++q) {
#pragma unroll
    for (int r = 0; r < 16; ++r) {
      float v = acc[q][r];
      v += __shfl_xor(v, 1);
      v += __shfl_xor(v, 2);
      v += __shfl_xor(v, 4);
      v += __shfl_xor(v, 8);
      v += __shfl_xor(v, 16);
      v += __shfl_xor(v, 32);
      acc[q][r] = v;
    }
    if (lane == 0) {
      int t = t0 + q;
      tokid[t] = ids[q];
#pragma unroll
      for (int r = 0; r < 16; ++r) {
        float v = sc[q] * acc[q][r];
        hbuf[t * RANK + r] = v;
        hb16[t * RANK + r] = f2bf(v);
      }
    }
  }
}

// ------------------------------------------------------------- main fused GEMM
// 256x256 tile, BK=32, 8 waves (2M x 4N), per-wave output 128x64.
// 4-deep LDS pipeline (4 bufs x (A 16KB + B 16KB) = 128 KB): during tile t,
// stage tile t+3; at tile end, COUNTED s_waitcnt vmcnt(8) (2 tiles in flight)
// + raw s_barrier -- the main loop never drains vmcnt to 0 (T4, m218).
// XOR swizzle for 64B rows: phys 16B-chunk = logical ^ ((row>>1)&3), applied
// inversely on the staging SOURCE address (rule #21); read is 2-way = free.
// Epilogue: LoRA term via one K=32 MFMA extension (A = masked h' bf16,
// B = wb rows of the block's <=2 adapters); scalar fallback for >=2-boundary
// blocks (rare).
__global__ __launch_bounds__(512, 2) void gemm_fused(const unsigned short* __restrict__ A,
                                                     const unsigned short* __restrict__ B,
                                                     const float* __restrict__ bias,
                                                     const float* __restrict__ hbuf,
                                                     const unsigned short* __restrict__ hb16,
                                                     const int* __restrict__ tokid,
                                                     const float* __restrict__ wbt,
                                                     float* __restrict__ out) {
  __shared__ __align__(16) unsigned short As[4][BM * BK];  // 4 x 16 KB
  __shared__ __align__(16) unsigned short Bs[4][BN * BK];  // 4 x 16 KB
  __shared__ int s_nb;

  const int tid = threadIdx.x;
  const int lane = tid & 63;
  const int wave = tid >> 6;   // 0..7
  const int wr = wave >> 2;    // 0..1  M half
  const int wn = wave & 3;     // 0..3  N quarter

  // XCD-aware bijective swizzle: 512 blocks, 64-block chunk per XCD
  const int bsw = (blockIdx.x & 7) * 64 + (blockIdx.x >> 3);
  const int brow = (bsw >> 4) * BM;   // 32 M-blocks
  const int bcol = (bsw & 15) * BN;   // 16 N-blocks

  f32x4 acc[8][4] = {};

  const int g = lane >> 4;              // k-group 0..3 (8 k each)
  const int rsel = lane & 15;           // fragment row select
  const int rphase = (rsel >> 1) & 3;   // swizzle phase for read rows

#define STAGE(p, kt)                                                                   \
  {                                                                                    \
    _Pragma("unroll")                                                                  \
    for (int i = 0; i < 2; ++i) {                                                      \
      const int lin = i * 512 + tid;           /* 0..1023 */                           \
      const int r = lin >> 2;                  /* row 0..255 */                        \
      const int klog = ((lin & 3) ^ ((r >> 1) & 3)) * 8;                               \
      const unsigned short* gA = A + (size_t)(brow + r) * DIN + (kt) + klog;           \
      const unsigned short* gB = B + (size_t)(bcol + r) * DIN + (kt) + klog;           \
      __builtin_amdgcn_global_load_lds(GLB_PTR(gA), LDS_PTR(&As[p][lin * 8]), 16, 0, 0); \
      __builtin_amdgcn_global_load_lds(GLB_PTR(gB), LDS_PTR(&Bs[p][lin * 8]), 16, 0, 0); \
    }                                                                                  \
  }

  STAGE(0, 0);
  STAGE(1, BK);
  STAGE(2, 2 * BK);
  asm volatile("s_waitcnt vmcnt(8)" ::: "memory");  // tile 0 landed; 1,2 in flight
  __builtin_amdgcn_s_barrier();
  asm volatile("" ::: "memory");

  for (int t = 0; t < NT; ++t) {
    const int p = t & 3;
    if (t + 3 < NT) STAGE((t + 3) & 3, (t + 3) * BK);

    const unsigned short* Asp = As[p];
    const unsigned short* Bsp = Bs[p];
    const int phys = (g ^ rphase) * 8;

    // b-frags: one read per n covers the whole BK=32
    bf16x8 bfr[4];
#pragma unroll
    for (int n = 0; n < 4; ++n)
      bfr[n] = *(const bf16x8*)(Bsp + (wn * 64 + n * 16 + rsel) * BK + phys);

#pragma unroll
    for (int ph = 0; ph < 2; ++ph) {
      bf16x8 afr[4];
#pragma unroll
      for (int mi = 0; mi < 4; ++mi)
        afr[mi] = *(const bf16x8*)(Asp + (wr * 128 + (ph * 4 + mi) * 16 + rsel) * BK + phys);
      __builtin_amdgcn_s_barrier();
      asm volatile("" ::: "memory");
      __builtin_amdgcn_s_setprio(1);
#pragma unroll
      for (int mi = 0; mi < 4; ++mi)
#pragma unroll
        for (int n = 0; n < 4; ++n)
          acc[ph * 4 + mi][n] = __builtin_amdgcn_mfma_f32_16x16x32_bf16(
              afr[mi], bfr[n], acc[ph * 4 + mi][n], 0, 0, 0);
      __builtin_amdgcn_s_setprio(0);
      __builtin_amdgcn_s_barrier();
    }

    // counted boundary wait: next tile's 4 loads landed, 2 newer tiles in flight
    if (t + 3 < NT)      { asm volatile("s_waitcnt vmcnt(8)" ::: "memory"); }
    else if (t + 2 < NT) { asm volatile("s_waitcnt vmcnt(4)" ::: "memory"); }
    else                 { asm volatile("s_waitcnt vmcnt(0)" ::: "memory"); }
    __builtin_amdgcn_s_barrier();
    asm volatile("" ::: "memory");
  }

  // ---- epilogue -------------------------------------------------------------
  const int rb = brow + wr * 128;
  const int cb = bcol + wn * 64;
  const int crow = g * 4;          // note: C/D row uses (lane>>4)*4
  const int ccol = rsel;

  // count adapter transitions in this block's 256 rows
  if (tid == 0) s_nb = 0;
  __syncthreads();
  if (tid >= 1 && tid < BM) {
    if (tokid[brow + tid] != tokid[brow + tid - 1]) atomicAdd(&s_nb, 1);
  }
  __syncthreads();
  const int nb = s_nb;
  const int idLo = tokid[brow];
  const int idHi = tokid[brow + BM - 1];

  float biasn[4];
#pragma unroll
  for (int n = 0; n < 4; ++n) biasn[n] = bias[cb + n * 16 + ccol];

  if (nb <= 1) {
    // ---- MFMA K=32 extension: k<16 -> adapter idLo, k>=16 -> adapter idHi
    const int myId = (g < 2) ? idLo : idHi;           // adapter for my k-group
    const int maskId = (g < 2) ? idLo : ((nb == 0) ? 0x80000000 : idHi);
    const float* wbase = wbt + (size_t)myId * RANK * DOUTF + (size_t)((g & 1) * 8) * DOUTF;
    bf16x8 bext[4];
#pragma unroll
    for (int n = 0; n < 4; ++n) {
      const int col = cb + n * 16 + ccol;
#pragma unroll
      for (int j = 0; j < 8; ++j)
        bext[n][j] = (short)f2bf(wbase[(size_t)j * DOUTF + col]);
    }
#pragma unroll
    for (int m = 0; m < 8; ++m) {
      const int row = rb + m * 16 + rsel;
      const int rid = tokid[row];
      bf16x8 av = {};
      if (rid == maskId)
        av = *(const bf16x8*)(hb16 + (size_t)row * RANK + (g & 1) * 8);
#pragma unroll
      for (int n = 0; n < 4; ++n)
        acc[m][n] = __builtin_amdgcn_mfma_f32_16x16x32_bf16(av, bext[n], acc[m][n], 0, 0, 0);
    }
    // ---- store
#pragma unroll
    for (int m = 0; m < 8; ++m) {
#pragma unroll
      for (int j = 0; j < 4; ++j) {
        const int row = rb + m * 16 + crow + j;
        float* orow = out + (size_t)row * DOUTF;
#pragma unroll
        for (int n = 0; n < 4; ++n)
          orow[cb + n * 16 + ccol] = acc[m][n][j] + biasn[n];
      }
    }
  } else {
    // ---- rare fallback: per-row scalar LoRA
#pragma unroll
    for (int m = 0; m < 8; ++m) {
#pragma unroll
      for (int j = 0; j < 4; ++j) {
        const int row = rb + m * 16 + crow + j;
        const float4* hp = (const float4*)(hbuf + (size_t)row * RANK);
        float4 h0 = hp[0], h1 = hp[1], h2 = hp[2], h3 = hp[3];
        float hv[16] = {h0.x, h0.y, h0.z, h0.w, h1.x, h1.y, h1.z, h1.w,
                        h2.x, h2.y, h2.z, h2.w, h3.x, h3.y, h3.z, h3.w};
        const float* wrow = wbt + (size_t)tokid[row] * RANK * DOUTF;
        float* orow = out + (size_t)row * DOUTF;
#pragma unroll
        for (int n = 0; n < 4; ++n) {
          const int col = cb + n * 16 + ccol;
          float v = acc[m][n][j] + biasn[n];
#pragma unroll
          for (int r = 0; r < 16; ++r) v += hv[r] * wrow[(size_t)r * DOUTF + col];
          orow[col] = v;
        }
      }
    }
  }
#undef STAGE
}

// ---------------------------------------------------------------------- launch
extern "C" void kernel_launch(void* const* d_in, const int* in_sizes, int n_in,
                              void* d_out, int out_size, void* d_ws, size_t ws_size,
                              hipStream_t stream) {
  const float* x       = (const float*)d_in[0];
  const float* base_w  = (const float*)d_in[1];
  const float* base_b  = (const float*)d_in[2];
  const float* wa      = (const float*)d_in[3];
  const float* wb      = (const float*)d_in[4];
  const float* scaling = (const float*)d_in[5];
  const int*   segment = (const int*)d_in[6];
  const int*   lora_id = (const int*)d_in[7];
  float* out = (float*)d_out;

  char* ws = (char*)d_ws;
  unsigned short* xb   = (unsigned short*)ws;                                  // 64 MB
  unsigned short* wbf  = (unsigned short*)(ws + (size_t)T_TOK * DIN * 2);      // 32 MB
  float* hbuf          = (float*)(ws + (size_t)T_TOK * DIN * 2 + (size_t)DOUTF * DIN * 2);
  int* tokid           = (int*)((char*)hbuf + (size_t)T_TOK * RANK * 4);
  unsigned short* hb16 = (unsigned short*)((char*)tokid + (size_t)T_TOK * 4);

  cvt_f32_bf16<<<2048, 256, 0, stream>>>(base_w, wbf, (DOUTF * DIN) / 8);
  lora_h<<<T_TOK / 16, 256, 0, stream>>>(x, wa, scaling, segment, lora_id, hbuf, hb16,
                                         tokid, xb);
  gemm_fused<<<(T_TOK / BM) * (DOUTF / BN), 512, 0, stream>>>(xb, wbf, base_b, hbuf,
                                                              hb16, tokid, wb, out);
}

// Round 5
// 448.475 us; speedup vs baseline: 2.2643x; 1.1522x over previous
//
#include <hip/hip_runtime.h>

#define T_TOK 8192
#define DIN   4096
#define DOUTF 4096
#define RANK  16

#define BM 256
#define BN 256
#define BK 32
#define NT (DIN / BK)  // 128 K-tiles

typedef __attribute__((ext_vector_type(4))) float f32x4;
typedef __attribute__((ext_vector_type(8))) short bf16x8;
typedef __attribute__((ext_vector_type(8))) unsigned short u16x8;

#define GLB_PTR(p) ((const __attribute__((address_space(1))) void*)(p))
#define LDS_PTR(p) ((__attribute__((address_space(3))) void*)(p))

__device__ __forceinline__ unsigned short f2bf(float f) {
  unsigned u = __float_as_uint(f);
  u = (u + 0x7fffu + ((u >> 16) & 1u)) >> 16;  // RNE
  return (unsigned short)u;
}

// ---------------------------------------------------------------- fp32 -> bf16
__global__ __launch_bounds__(256) void cvt_f32_bf16(const float* __restrict__ in,
                                                    unsigned short* __restrict__ out,
                                                    int n8) {
  const int stride = gridDim.x * blockDim.x;
  for (int i = blockIdx.x * blockDim.x + threadIdx.x; i < n8; i += stride) {
    const float4* p = (const float4*)(in + (size_t)i * 8);
    float4 a = p[0], b = p[1];
    u16x8 r;
    r[0] = f2bf(a.x); r[1] = f2bf(a.y); r[2] = f2bf(a.z); r[3] = f2bf(a.w);
    r[4] = f2bf(b.x); r[5] = f2bf(b.y); r[6] = f2bf(b.z); r[7] = f2bf(b.w);
    *(u16x8*)(out + (size_t)i * 8) = r;
  }
}

// ----------------- h'[t,r] = scaling * x @ wa[id_t]; emits x bf16 + h' bf16 ---
// 4 waves/block, 4 consecutive tokens per wave. Lane owns d = it*256 + lane*4
// (float4 x loads, ushort4 xb stores -- G13 vectorization).
__global__ __launch_bounds__(256) void lora_h(const float* __restrict__ x,
                                              const float* __restrict__ wa,
                                              const float* __restrict__ scaling,
                                              const int* __restrict__ segment,
                                              const int* __restrict__ lora_ids,
                                              float* __restrict__ hbuf,
                                              unsigned short* __restrict__ hb16,
                                              int* __restrict__ tokid,
                                              unsigned short* __restrict__ xb) {
  const int lane = threadIdx.x & 63;
  const int wave = threadIdx.x >> 6;
  const int t0 = blockIdx.x * 16 + wave * 4;

  int ids[4]; float sc[4];
#pragma unroll
  for (int q = 0; q < 4; ++q) {
    int t = t0 + q;
    int s = 0;
#pragma unroll
    for (int i = 1; i < 8; ++i)
      if (t >= segment[i]) s = i;
    int id = lora_ids[s];
    ids[q] = id;
    sc[q] = scaling[id];
  }

  float acc[4][16];
#pragma unroll
  for (int q = 0; q < 4; ++q)
#pragma unroll
    for (int r = 0; r < 16; ++r) acc[q][r] = 0.f;

  const bool same = (ids[0] == ids[1]) && (ids[1] == ids[2]) && (ids[2] == ids[3]);
  const int dbase = lane * 4;

  if (same) {
    const float* wrow = wa + (size_t)ids[0] * DIN * RANK;
#pragma unroll 2
    for (int it = 0; it < 16; ++it) {
      const int d = it * 256 + dbase;
      f32x4 xv[4];
#pragma unroll
      for (int q = 0; q < 4; ++q) {
        xv[q] = *(const f32x4*)(x + (size_t)(t0 + q) * DIN + d);
        ushort4 s4 = {f2bf(xv[q][0]), f2bf(xv[q][1]), f2bf(xv[q][2]), f2bf(xv[q][3])};
        *(ushort4*)(xb + (size_t)(t0 + q) * DIN + d) = s4;
      }
#pragma unroll
      for (int dd = 0; dd < 4; ++dd) {
        const f32x4* wp = (const f32x4*)(wrow + (size_t)(d + dd) * RANK);
        f32x4 w0 = wp[0], w1 = wp[1], w2 = wp[2], w3 = wp[3];
#pragma unroll
        for (int q = 0; q < 4; ++q) {
          const float xs = xv[q][dd];
#pragma unroll
          for (int r = 0; r < 4; ++r) {
            acc[q][r]      += xs * w0[r];
            acc[q][r + 4]  += xs * w1[r];
            acc[q][r + 8]  += xs * w2[r];
            acc[q][r + 12] += xs * w3[r];
          }
        }
      }
    }
  } else {
#pragma unroll
    for (int q = 0; q < 4; ++q) {
      const float* wrow = wa + (size_t)ids[q] * DIN * RANK;
      for (int it = 0; it < 16; ++it) {
        const int d = it * 256 + dbase;
        f32x4 xv = *(const f32x4*)(x + (size_t)(t0 + q) * DIN + d);
        ushort4 s4 = {f2bf(xv[0]), f2bf(xv[1]), f2bf(xv[2]), f2bf(xv[3])};
        *(ushort4*)(xb + (size_t)(t0 + q) * DIN + d) = s4;
#pragma unroll
        for (int dd = 0; dd < 4; ++dd) {
          const f32x4* wp = (const f32x4*)(wrow + (size_t)(d + dd) * RANK);
          f32x4 w0 = wp[0], w1 = wp[1], w2 = wp[2], w3 = wp[3];
          const float xs = xv[dd];
#pragma unroll
          for (int r = 0; r < 4; ++r) {
            acc[q][r]      += xs * w0[r];
            acc[q][r + 4]  += xs * w1[r];
            acc[q][r + 8]  += xs * w2[r];
            acc[q][r + 12] += xs * w3[r];
          }
        }
      }
    }
  }

#pragma unroll
  for (int q = 0; q < 4; ++q) {
#pragma unroll
    for (int r = 0; r < 16; ++r) {
      float v = acc[q][r];
      v += __shfl_xor(v, 1);
      v += __shfl_xor(v, 2);
      v += __shfl_xor(v, 4);
      v += __shfl_xor(v, 8);
      v += __shfl_xor(v, 16);
      v += __shfl_xor(v, 32);
      acc[q][r] = v;
    }
    if (lane == 0) {
      int t = t0 + q;
      tokid[t] = ids[q];
#pragma unroll
      for (int r = 0; r < 16; ++r) {
        float v = sc[q] * acc[q][r];
        hbuf[t * RANK + r] = v;
        hb16[t * RANK + r] = f2bf(v);
      }
    }
  }
}

// ------------------------------------------------------------- main fused GEMM
// 256x256 tile, BK=32, 8 waves (2M x 4N), per-wave output 128x64.
// 4-deep LDS pipeline with COUNTED s_waitcnt vmcnt(8) (never drains to 0 in
// the main loop -- T4). NO intra-tile barriers: all 12 ds_reads issue upfront,
// the compiler's fine-grained lgkmcnt lets MFMA cluster 0 start after its 8
// reads while the rest are in flight, and waves drift so one wave's LDS burst
// overlaps another's MFMA cluster (m114 overlap; setprio arbitration -- T5).
// Only sync per K-tile: counted vmcnt + one s_barrier (guards the staging
// write into tile (t-1)'s buffer -- every wave's t-1 reads were lgkm-drained
// before its MFMAs, hence before it reaches the barrier).
// XOR swizzle (64B rows): phys 16B-chunk = logical ^ ((row>>1)&3) on BOTH the
// staging source and the ds_read (rule #21; round-4-proven 0 conflicts).
__global__ __launch_bounds__(512, 2) void gemm_fused(const unsigned short* __restrict__ A,
                                                     const unsigned short* __restrict__ B,
                                                     const float* __restrict__ bias,
                                                     const float* __restrict__ hbuf,
                                                     const unsigned short* __restrict__ hb16,
                                                     const int* __restrict__ tokid,
                                                     const float* __restrict__ wbt,
                                                     float* __restrict__ out) {
  __shared__ __align__(16) unsigned short As[4][BM * BK];  // 4 x 16 KB
  __shared__ __align__(16) unsigned short Bs[4][BN * BK];  // 4 x 16 KB
  __shared__ int s_nb;

  const int tid = threadIdx.x;
  const int lane = tid & 63;
  const int wave = tid >> 6;   // 0..7
  const int wr = wave >> 2;    // 0..1  M half
  const int wn = wave & 3;     // 0..3  N quarter

  // XCD-aware bijective swizzle: 512 blocks, 64-block chunk per XCD
  const int bsw = (blockIdx.x & 7) * 64 + (blockIdx.x >> 3);
  const int brow = (bsw >> 4) * BM;   // 32 M-blocks
  const int bcol = (bsw & 15) * BN;   // 16 N-blocks

  f32x4 acc[8][4] = {};

  const int g = lane >> 4;              // k-group 0..3 (8 k each)
  const int rsel = lane & 15;           // fragment row select
  const int rphase = (rsel >> 1) & 3;   // swizzle phase for read rows

#define STAGE(p, kt)                                                                   \
  {                                                                                    \
    _Pragma("unroll")                                                                  \
    for (int i = 0; i < 2; ++i) {                                                      \
      const int lin = i * 512 + tid;           /* 0..1023 */                           \
      const int r = lin >> 2;                  /* row 0..255 */                        \
      const int klog = ((lin & 3) ^ ((r >> 1) & 3)) * 8;                               \
      const unsigned short* gA = A + (size_t)(brow + r) * DIN + (kt) + klog;           \
      const unsigned short* gB = B + (size_t)(bcol + r) * DIN + (kt) + klog;           \
      __builtin_amdgcn_global_load_lds(GLB_PTR(gA), LDS_PTR(&As[p][lin * 8]), 16, 0, 0); \
      __builtin_amdgcn_global_load_lds(GLB_PTR(gB), LDS_PTR(&Bs[p][lin * 8]), 16, 0, 0); \
    }                                                                                  \
  }

  STAGE(0, 0);
  STAGE(1, BK);
  STAGE(2, 2 * BK);
  asm volatile("s_waitcnt vmcnt(8)" ::: "memory");  // tile 0 landed; 1,2 in flight
  __builtin_amdgcn_s_barrier();
  asm volatile("" ::: "memory");

  for (int t = 0; t < NT; ++t) {
    const int p = t & 3;
    if (t + 3 < NT) STAGE((t + 3) & 3, (t + 3) * BK);

    const unsigned short* Asp = As[p];
    const unsigned short* Bsp = Bs[p];
    const int phys = (g ^ rphase) * 8;

    // all 12 ds_reads issued upfront; compiler's counted lgkmcnt lets the
    // first MFMA cluster start after the first 8 land
    bf16x8 bfr[4];
#pragma unroll
    for (int n = 0; n < 4; ++n)
      bfr[n] = *(const bf16x8*)(Bsp + (wn * 64 + n * 16 + rsel) * BK + phys);
    bf16x8 afr0[4], afr1[4];
#pragma unroll
    for (int mi = 0; mi < 4; ++mi)
      afr0[mi] = *(const bf16x8*)(Asp + (wr * 128 + mi * 16 + rsel) * BK + phys);
#pragma unroll
    for (int mi = 0; mi < 4; ++mi)
      afr1[mi] = *(const bf16x8*)(Asp + (wr * 128 + (4 + mi) * 16 + rsel) * BK + phys);

    __builtin_amdgcn_s_setprio(1);
#pragma unroll
    for (int mi = 0; mi < 4; ++mi)
#pragma unroll
      for (int n = 0; n < 4; ++n)
        acc[mi][n] = __builtin_amdgcn_mfma_f32_16x16x32_bf16(afr0[mi], bfr[n], acc[mi][n], 0, 0, 0);
    __builtin_amdgcn_s_setprio(0);

    __builtin_amdgcn_s_setprio(1);
#pragma unroll
    for (int mi = 0; mi < 4; ++mi)
#pragma unroll
      for (int n = 0; n < 4; ++n)
        acc[4 + mi][n] = __builtin_amdgcn_mfma_f32_16x16x32_bf16(afr1[mi], bfr[n], acc[4 + mi][n], 0, 0, 0);
    __builtin_amdgcn_s_setprio(0);

    // counted boundary wait: tile t+1's loads landed, 2 newer tiles in flight
    if (t + 3 < NT)      { asm volatile("s_waitcnt vmcnt(8)" ::: "memory"); }
    else if (t + 2 < NT) { asm volatile("s_waitcnt vmcnt(4)" ::: "memory"); }
    else                 { asm volatile("s_waitcnt vmcnt(0)" ::: "memory"); }
    __builtin_amdgcn_s_barrier();
    asm volatile("" ::: "memory");
  }

  // ---- epilogue -------------------------------------------------------------
  const int rb = brow + wr * 128;
  const int cb = bcol + wn * 64;
  const int crow = g * 4;          // C/D row = (lane>>4)*4 + j
  const int ccol = rsel;

  // count adapter transitions in this block's 256 rows
  if (tid == 0) s_nb = 0;
  __syncthreads();
  if (tid >= 1 && tid < BM) {
    if (tokid[brow + tid] != tokid[brow + tid - 1]) atomicAdd(&s_nb, 1);
  }
  __syncthreads();
  const int nb = s_nb;
  const int idLo = tokid[brow];
  const int idHi = tokid[brow + BM - 1];

  float biasn[4];
#pragma unroll
  for (int n = 0; n < 4; ++n) biasn[n] = bias[cb + n * 16 + ccol];

  if (nb <= 1) {
    // ---- MFMA K=32 extension: k<16 -> adapter idLo, k>=16 -> adapter idHi
    const int myId = (g < 2) ? idLo : idHi;           // adapter for my k-group
    const int maskId = (g < 2) ? idLo : ((nb == 0) ? 0x80000000 : idHi);
    const float* wbase = wbt + (size_t)myId * RANK * DOUTF + (size_t)((g & 1) * 8) * DOUTF;
    bf16x8 bext[4];
#pragma unroll
    for (int n = 0; n < 4; ++n) {
      const int col = cb + n * 16 + ccol;
#pragma unroll
      for (int j = 0; j < 8; ++j)
        bext[n][j] = (short)f2bf(wbase[(size_t)j * DOUTF + col]);
    }
#pragma unroll
    for (int m = 0; m < 8; ++m) {
      const int row = rb + m * 16 + rsel;
      const int rid = tokid[row];
      bf16x8 av = {};
      if (rid == maskId)
        av = *(const bf16x8*)(hb16 + (size_t)row * RANK + (g & 1) * 8);
#pragma unroll
      for (int n = 0; n < 4; ++n)
        acc[m][n] = __builtin_amdgcn_mfma_f32_16x16x32_bf16(av, bext[n], acc[m][n], 0, 0, 0);
    }
    // ---- store
#pragma unroll
    for (int m = 0; m < 8; ++m) {
#pragma unroll
      for (int j = 0; j < 4; ++j) {
        const int row = rb + m * 16 + crow + j;
        float* orow = out + (size_t)row * DOUTF;
#pragma unroll
        for (int n = 0; n < 4; ++n)
          orow[cb + n * 16 + ccol] = acc[m][n][j] + biasn[n];
      }
    }
  } else {
    // ---- rare fallback: per-row scalar LoRA
#pragma unroll
    for (int m = 0; m < 8; ++m) {
#pragma unroll
      for (int j = 0; j < 4; ++j) {
        const int row = rb + m * 16 + crow + j;
        const float4* hp = (const float4*)(hbuf + (size_t)row * RANK);
        float4 h0 = hp[0], h1 = hp[1], h2 = hp[2], h3 = hp[3];
        float hv[16] = {h0.x, h0.y, h0.z, h0.w, h1.x, h1.y, h1.z, h1.w,
                        h2.x, h2.y, h2.z, h2.w, h3.x, h3.y, h3.z, h3.w};
        const float* wrow = wbt + (size_t)tokid[row] * RANK * DOUTF;
        float* orow = out + (size_t)row * DOUTF;
#pragma unroll
        for (int n = 0; n < 4; ++n) {
          const int col = cb + n * 16 + ccol;
          float v = acc[m][n][j] + biasn[n];
#pragma unroll
          for (int r = 0; r < 16; ++r) v += hv[r] * wrow[(size_t)r * DOUTF + col];
          orow[col] = v;
        }
      }
    }
  }
#undef STAGE
}

// ---------------------------------------------------------------------- launch
extern "C" void kernel_launch(void* const* d_in, const int* in_sizes, int n_in,
                              void* d_out, int out_size, void* d_ws, size_t ws_size,
                              hipStream_t stream) {
  const float* x       = (const float*)d_in[0];
  const float* base_w  = (const float*)d_in[1];
  const float* base_b  = (const float*)d_in[2];
  const float* wa      = (const float*)d_in[3];
  const float* wb      = (const float*)d_in[4];
  const float* scaling = (const float*)d_in[5];
  const int*   segment = (const int*)d_in[6];
  const int*   lora_id = (const int*)d_in[7];
  float* out = (float*)d_out;

  char* ws = (char*)d_ws;
  unsigned short* xb   = (unsigned short*)ws;                                  // 64 MB
  unsigned short* wbf  = (unsigned short*)(ws + (size_t)T_TOK * DIN * 2);      // 32 MB
  float* hbuf          = (float*)(ws + (size_t)T_TOK * DIN * 2 + (size_t)DOUTF * DIN * 2);
  int* tokid           = (int*)((char*)hbuf + (size_t)T_TOK * RANK * 4);
  unsigned short* hb16 = (unsigned short*)((char*)tokid + (size_t)T_TOK * 4);

  cvt_f32_bf16<<<2048, 256, 0, stream>>>(base_w, wbf, (DOUTF * DIN) / 8);
  lora_h<<<T_TOK / 16, 256, 0, stream>>>(x, wa, scaling, segment, lora_id, hbuf, hb16,
                                         tokid, xb);
  gemm_fused<<<(T_TOK / BM) * (DOUTF / BN), 512, 0, stream>>>(xb, wbf, base_b, hbuf,
                                                              hb16, tokid, wb, out);
}

// Round 6
// 420.807 us; speedup vs baseline: 2.4131x; 1.0657x over previous
//
#include <hip/hip_runtime.h>

#define T_TOK 8192
#define DIN   4096
#define DOUTF 4096
#define RANK  16

#define BM 256
#define BN 256
#define BK 64
#define NT (DIN / BK)   // 64 K-tiles
#define NPAIR (NT / 2)  // 32 iterations, 2 K-tiles each

typedef __attribute__((ext_vector_type(4))) float f32x4;
typedef __attribute__((ext_vector_type(8))) short bf16x8;
typedef __attribute__((ext_vector_type(8))) unsigned short u16x8;

#define GLB_PTR(p) ((const __attribute__((address_space(1))) void*)(p))
#define LDS_PTR(p) ((__attribute__((address_space(3))) void*)(p))

__device__ __forceinline__ unsigned short f2bf(float f) {
  unsigned u = __float_as_uint(f);
  u = (u + 0x7fffu + ((u >> 16) & 1u)) >> 16;  // RNE
  return (unsigned short)u;
}

// ---------------------------------------------------------------- fp32 -> bf16
__global__ __launch_bounds__(256) void cvt_f32_bf16(const float* __restrict__ in,
                                                    unsigned short* __restrict__ out,
                                                    int n8) {
  const int stride = gridDim.x * blockDim.x;
  for (int i = blockIdx.x * blockDim.x + threadIdx.x; i < n8; i += stride) {
    const float4* p = (const float4*)(in + (size_t)i * 8);
    float4 a = p[0], b = p[1];
    u16x8 r;
    r[0] = f2bf(a.x); r[1] = f2bf(a.y); r[2] = f2bf(a.z); r[3] = f2bf(a.w);
    r[4] = f2bf(b.x); r[5] = f2bf(b.y); r[6] = f2bf(b.z); r[7] = f2bf(b.w);
    *(u16x8*)(out + (size_t)i * 8) = r;
  }
}

// ----------------- h'[t,r] = scaling * x @ wa[id_t]; emits x bf16 + h' bf16 ---
__global__ __launch_bounds__(256) void lora_h(const float* __restrict__ x,
                                              const float* __restrict__ wa,
                                              const float* __restrict__ scaling,
                                              const int* __restrict__ segment,
                                              const int* __restrict__ lora_ids,
                                              float* __restrict__ hbuf,
                                              unsigned short* __restrict__ hb16,
                                              int* __restrict__ tokid,
                                              unsigned short* __restrict__ xb) {
  const int lane = threadIdx.x & 63;
  const int wave = threadIdx.x >> 6;
  const int t0 = blockIdx.x * 16 + wave * 4;

  int ids[4]; float sc[4];
#pragma unroll
  for (int q = 0; q < 4; ++q) {
    int t = t0 + q;
    int s = 0;
#pragma unroll
    for (int i = 1; i < 8; ++i)
      if (t >= segment[i]) s = i;
    int id = lora_ids[s];
    ids[q] = id;
    sc[q] = scaling[id];
  }

  float acc[4][16];
#pragma unroll
  for (int q = 0; q < 4; ++q)
#pragma unroll
    for (int r = 0; r < 16; ++r) acc[q][r] = 0.f;

  const bool same = (ids[0] == ids[1]) && (ids[1] == ids[2]) && (ids[2] == ids[3]);
  const int dbase = lane * 4;

  if (same) {
    const float* wrow = wa + (size_t)ids[0] * DIN * RANK;
#pragma unroll 2
    for (int it = 0; it < 16; ++it) {
      const int d = it * 256 + dbase;
      f32x4 xv[4];
#pragma unroll
      for (int q = 0; q < 4; ++q) {
        xv[q] = *(const f32x4*)(x + (size_t)(t0 + q) * DIN + d);
        ushort4 s4 = {f2bf(xv[q][0]), f2bf(xv[q][1]), f2bf(xv[q][2]), f2bf(xv[q][3])};
        *(ushort4*)(xb + (size_t)(t0 + q) * DIN + d) = s4;
      }
#pragma unroll
      for (int dd = 0; dd < 4; ++dd) {
        const f32x4* wp = (const f32x4*)(wrow + (size_t)(d + dd) * RANK);
        f32x4 w0 = wp[0], w1 = wp[1], w2 = wp[2], w3 = wp[3];
#pragma unroll
        for (int q = 0; q < 4; ++q) {
          const float xs = xv[q][dd];
#pragma unroll
          for (int r = 0; r < 4; ++r) {
            acc[q][r]      += xs * w0[r];
            acc[q][r + 4]  += xs * w1[r];
            acc[q][r + 8]  += xs * w2[r];
            acc[q][r + 12] += xs * w3[r];
          }
        }
      }
    }
  } else {
#pragma unroll
    for (int q = 0; q < 4; ++q) {
      const float* wrow = wa + (size_t)ids[q] * DIN * RANK;
      for (int it = 0; it < 16; ++it) {
        const int d = it * 256 + dbase;
        f32x4 xv = *(const f32x4*)(x + (size_t)(t0 + q) * DIN + d);
        ushort4 s4 = {f2bf(xv[0]), f2bf(xv[1]), f2bf(xv[2]), f2bf(xv[3])};
        *(ushort4*)(xb + (size_t)(t0 + q) * DIN + d) = s4;
#pragma unroll
        for (int dd = 0; dd < 4; ++dd) {
          const f32x4* wp = (const f32x4*)(wrow + (size_t)(d + dd) * RANK);
          f32x4 w0 = wp[0], w1 = wp[1], w2 = wp[2], w3 = wp[3];
          const float xs = xv[dd];
#pragma unroll
          for (int r = 0; r < 4; ++r) {
            acc[q][r]      += xs * w0[r];
            acc[q][r + 4]  += xs * w1[r];
            acc[q][r + 8]  += xs * w2[r];
            acc[q][r + 12] += xs * w3[r];
          }
        }
      }
    }
  }

#pragma unroll
  for (int q = 0; q < 4; ++q) {
#pragma unroll
    for (int r = 0; r < 16; ++r) {
      float v = acc[q][r];
      v += __shfl_xor(v, 1);
      v += __shfl_xor(v, 2);
      v += __shfl_xor(v, 4);
      v += __shfl_xor(v, 8);
      v += __shfl_xor(v, 16);
      v += __shfl_xor(v, 32);
      acc[q][r] = v;
    }
    if (lane == 0) {
      int t = t0 + q;
      tokid[t] = ids[q];
#pragma unroll
      for (int r = 0; r < 16; ++r) {
        float v = sc[q] * acc[q][r];
        hbuf[t * RANK + r] = v;
        hb16[t * RANK + r] = f2bf(v);
      }
    }
  }
}

// ------------------------------------------------------------- main fused GEMM
// 256x256 tile, BK=64, 8 waves (2M x 4N), per-wave output 128x64.
// m201-faithful 8-phase / 2-K-tile schedule, 2 LDS buffers (buf0=even tile u,
// buf1=odd tile v), 128 KB total. Each phase: {ds_read subtile; stage ONE
// half-tile (2 x global_load_lds); raw s_barrier; lgkmcnt(0); setprio(1);
// 16 MFMA; setprio(0); raw s_barrier}. Reads: ph0: b(all kk)+a m0-3 kk0;
// ph1: a m4-7 kk0; ph2: a m0-3 kk1; ph3: a m4-7 kk1; ph4-7 same on buf1.
// Stage slots (race-free: each target region's readers drained by an earlier
// phase's lgkm(0)+barrier): ph0,1: A(v)->buf1; ph2,3: B(u+2)->buf0;
// ph4,5: A(u+2)->buf0; ph6,7: B(v+2)->buf1.
// Counted waits ONLY at ph3/ph7 tails: vmcnt(4) (2 halves in flight; the
// halves needed by the next read phase landed; ~2-phase slack > HBM latency).
// XOR swizzle (128B rows, 8 chunks): phys = logical ^ (row&7), applied on the
// staging SOURCE address and the ds_read (rule #21; r2-proven 0 conflicts).
__global__ __launch_bounds__(512, 2) void gemm_fused(const unsigned short* __restrict__ A_,
                                                     const unsigned short* __restrict__ B_,
                                                     const float* __restrict__ bias,
                                                     const float* __restrict__ hbuf,
                                                     const unsigned short* __restrict__ hb16,
                                                     const int* __restrict__ tokid,
                                                     const float* __restrict__ wbt,
                                                     float* __restrict__ out) {
  __shared__ __align__(16) unsigned short As[2][BM * BK];  // 2 x 32 KB
  __shared__ __align__(16) unsigned short Bs[2][BN * BK];  // 2 x 32 KB
  __shared__ int s_nb;

  const int tid = threadIdx.x;
  const int lane = tid & 63;
  const int wave = tid >> 6;   // 0..7
  const int wr = wave >> 2;    // 0..1  M half
  const int wn = wave & 3;     // 0..3  N quarter

  // XCD-aware bijective swizzle: 512 blocks, 64-block chunk per XCD
  const int bsw = (blockIdx.x & 7) * 64 + (blockIdx.x >> 3);
  const int brow = (bsw >> 4) * BM;   // 32 M-blocks
  const int bcol = (bsw & 15) * BN;   // 16 N-blocks

  f32x4 acc[8][4] = {};

  const int g = lane >> 4;       // k-group 0..3
  const int rsel = lane & 15;    // fragment row select
  const int low3 = rsel & 7;     // swizzle phase (row & 7)

// stage ONE half-tile (128 rows x 64 k) of tile tt into dst[bufp], half h.
// LDS dest linear (base + lane*16); source chunk XOR-swizzled.
#define STAGE1(dst, bufp, h, tt, src, rb0)                                             \
  {                                                                                    \
    _Pragma("unroll")                                                                  \
    for (int i = 0; i < 2; ++i) {                                                      \
      const int lin2 = i * 512 + tid;                                                  \
      const int rr = lin2 >> 3;                                                        \
      const int klog = ((lin2 & 7) ^ (rr & 7)) * 8;                                    \
      const unsigned short* gp = (src) + (size_t)((rb0) + (h) * 128 + rr) * DIN + (tt) * BK + klog; \
      __builtin_amdgcn_global_load_lds(GLB_PTR(gp), LDS_PTR(&dst[bufp][(h) * 8192 + lin2 * 8]), 16, 0, 0); \
    }                                                                                  \
  }

#define RD_B(p)                                                                        \
  _Pragma("unroll") for (int kk = 0; kk < 2; ++kk)                                     \
  _Pragma("unroll") for (int n = 0; n < 4; ++n)                                        \
    bfr[n][kk] = *(const bf16x8*)(&Bs[p][(wn * 64 + n * 16 + rsel) * 64 + (((kk) * 4 + g) ^ low3) * 8]);

#define RD_A(AF, p, mo, kk)                                                            \
  _Pragma("unroll") for (int mi = 0; mi < 4; ++mi)                                     \
    AF[mi] = *(const bf16x8*)(&As[p][(wr * 128 + ((mo) + mi) * 16 + rsel) * 64 + (((kk) * 4 + g) ^ low3) * 8]);

#define MFMA16(mo, kk, AF)                                                             \
  _Pragma("unroll") for (int mi = 0; mi < 4; ++mi)                                     \
  _Pragma("unroll") for (int n = 0; n < 4; ++n)                                        \
    acc[(mo) + mi][n] = __builtin_amdgcn_mfma_f32_16x16x32_bf16(AF[mi], bfr[n][kk],    \
                                                                acc[(mo) + mi][n], 0, 0, 0);

#define PH_OPEN()                                                                      \
  asm volatile("" ::: "memory");                                                       \
  __builtin_amdgcn_s_barrier();                                                        \
  asm volatile("s_waitcnt lgkmcnt(0)" ::: "memory");                                   \
  __builtin_amdgcn_sched_barrier(0);                                                   \
  __builtin_amdgcn_s_setprio(1)

#define PH_CLOSE()                                                                     \
  __builtin_amdgcn_s_setprio(0);                                                       \
  asm volatile("" ::: "memory");                                                       \
  __builtin_amdgcn_s_barrier();                                                        \
  asm volatile("" ::: "memory")

#define PH_CLOSE_VM(N)                                                                 \
  __builtin_amdgcn_s_setprio(0);                                                       \
  asm volatile("s_waitcnt vmcnt(" #N ")" ::: "memory");                                \
  __builtin_amdgcn_s_barrier();                                                        \
  asm volatile("" ::: "memory")

  // ---- prologue: tile0 (all 4 halves) -> buf0; B halves of tile1 -> buf1
  STAGE1(As, 0, 0, 0, A_, brow);
  STAGE1(As, 0, 1, 0, A_, brow);
  STAGE1(Bs, 0, 0, 0, B_, bcol);
  STAGE1(Bs, 0, 1, 0, B_, bcol);
  STAGE1(Bs, 1, 0, 1, B_, bcol);
  STAGE1(Bs, 1, 1, 1, B_, bcol);
  asm volatile("s_waitcnt vmcnt(4)" ::: "memory");  // tile0 landed; B(1) in flight
  __builtin_amdgcn_s_barrier();
  asm volatile("" ::: "memory");

  for (int j = 0; j < NPAIR - 1; ++j) {
    const int u = 2 * j, v = u + 1;
    bf16x8 bfr[4][2], afA[4], afB[4];
    // ph0: buf0 kk0 m0-3; stage A0(v)->buf1
    RD_B(0); RD_A(afA, 0, 0, 0);
    STAGE1(As, 1, 0, v, A_, brow);
    PH_OPEN(); MFMA16(0, 0, afA); PH_CLOSE();
    // ph1: stage A1(v)->buf1
    RD_A(afB, 0, 4, 0);
    STAGE1(As, 1, 1, v, A_, brow);
    PH_OPEN(); MFMA16(4, 0, afB); PH_CLOSE();
    // ph2: stage B0(u+2)->buf0
    RD_A(afA, 0, 0, 1);
    STAGE1(Bs, 0, 0, u + 2, B_, bcol);
    PH_OPEN(); MFMA16(0, 1, afA); PH_CLOSE();
    // ph3: stage B1(u+2)->buf0 ; counted wait
    RD_A(afB, 0, 4, 1);
    STAGE1(Bs, 0, 1, u + 2, B_, bcol);
    PH_OPEN(); MFMA16(4, 1, afB); PH_CLOSE_VM(4);
    // ph4: buf1 kk0 m0-3; stage A0(u+2)->buf0
    RD_B(1); RD_A(afA, 1, 0, 0);
    STAGE1(As, 0, 0, u + 2, A_, brow);
    PH_OPEN(); MFMA16(0, 0, afA); PH_CLOSE();
    // ph5: stage A1(u+2)->buf0
    RD_A(afB, 1, 4, 0);
    STAGE1(As, 0, 1, u + 2, A_, brow);
    PH_OPEN(); MFMA16(4, 0, afB); PH_CLOSE();
    // ph6: stage B0(v+2)->buf1
    RD_A(afA, 1, 0, 1);
    STAGE1(Bs, 1, 0, v + 2, B_, bcol);
    PH_OPEN(); MFMA16(0, 1, afA); PH_CLOSE();
    // ph7: stage B1(v+2)->buf1 ; counted wait
    RD_A(afB, 1, 4, 1);
    STAGE1(Bs, 1, 1, v + 2, B_, bcol);
    PH_OPEN(); MFMA16(4, 1, afB); PH_CLOSE_VM(4);
  }

  // ---- final iteration (u = NT-2, v = NT-1): stage only A(v); drain at ph3
  {
    const int v = NT - 1;
    bf16x8 bfr[4][2], afA[4], afB[4];
    RD_B(0); RD_A(afA, 0, 0, 0);
    STAGE1(As, 1, 0, v, A_, brow);
    PH_OPEN(); MFMA16(0, 0, afA); PH_CLOSE();
    RD_A(afB, 0, 4, 0);
    STAGE1(As, 1, 1, v, A_, brow);
    PH_OPEN(); MFMA16(4, 0, afB); PH_CLOSE();
    RD_A(afA, 0, 0, 1);
    PH_OPEN(); MFMA16(0, 1, afA); PH_CLOSE();
    RD_A(afB, 0, 4, 1);
    PH_OPEN(); MFMA16(4, 1, afB); PH_CLOSE_VM(0);
    RD_B(1); RD_A(afA, 1, 0, 0);
    PH_OPEN(); MFMA16(0, 0, afA); PH_CLOSE();
    RD_A(afB, 1, 4, 0);
    PH_OPEN(); MFMA16(4, 0, afB); PH_CLOSE();
    RD_A(afA, 1, 0, 1);
    PH_OPEN(); MFMA16(0, 1, afA); PH_CLOSE();
    RD_A(afB, 1, 4, 1);
    PH_OPEN(); MFMA16(4, 1, afB); PH_CLOSE();
  }

  // ---- epilogue -------------------------------------------------------------
  const int rb = brow + wr * 128;
  const int cb = bcol + wn * 64;
  const int crow = g * 4;          // C/D row = (lane>>4)*4 + j
  const int ccol = rsel;

  // count adapter transitions in this block's 256 rows
  if (tid == 0) s_nb = 0;
  __syncthreads();
  if (tid >= 1 && tid < BM) {
    if (tokid[brow + tid] != tokid[brow + tid - 1]) atomicAdd(&s_nb, 1);
  }
  __syncthreads();
  const int nb = s_nb;
  const int idLo = tokid[brow];
  const int idHi = tokid[brow + BM - 1];

  float biasn[4];
#pragma unroll
  for (int n = 0; n < 4; ++n) biasn[n] = bias[cb + n * 16 + ccol];

  if (nb <= 1) {
    // ---- MFMA K=32 extension: k<16 -> adapter idLo, k>=16 -> adapter idHi
    const int myId = (g < 2) ? idLo : idHi;
    const int maskId = (g < 2) ? idLo : ((nb == 0) ? 0x80000000 : idHi);
    const float* wbase = wbt + (size_t)myId * RANK * DOUTF + (size_t)((g & 1) * 8) * DOUTF;
    bf16x8 bext[4];
#pragma unroll
    for (int n = 0; n < 4; ++n) {
      const int col = cb + n * 16 + ccol;
#pragma unroll
      for (int j = 0; j < 8; ++j)
        bext[n][j] = (short)f2bf(wbase[(size_t)j * DOUTF + col]);
    }
#pragma unroll
    for (int m = 0; m < 8; ++m) {
      const int row = rb + m * 16 + rsel;
      const int rid = tokid[row];
      bf16x8 av = {};
      if (rid == maskId)
        av = *(const bf16x8*)(hb16 + (size_t)row * RANK + (g & 1) * 8);
#pragma unroll
      for (int n = 0; n < 4; ++n)
        acc[m][n] = __builtin_amdgcn_mfma_f32_16x16x32_bf16(av, bext[n], acc[m][n], 0, 0, 0);
    }
#pragma unroll
    for (int m = 0; m < 8; ++m) {
#pragma unroll
      for (int j = 0; j < 4; ++j) {
        const int row = rb + m * 16 + crow + j;
        float* orow = out + (size_t)row * DOUTF;
#pragma unroll
        for (int n = 0; n < 4; ++n)
          orow[cb + n * 16 + ccol] = acc[m][n][j] + biasn[n];
      }
    }
  } else {
    // ---- rare fallback: per-row scalar LoRA
#pragma unroll
    for (int m = 0; m < 8; ++m) {
#pragma unroll
      for (int j = 0; j < 4; ++j) {
        const int row = rb + m * 16 + crow + j;
        const float4* hp = (const float4*)(hbuf + (size_t)row * RANK);
        float4 h0 = hp[0], h1 = hp[1], h2 = hp[2], h3 = hp[3];
        float hv[16] = {h0.x, h0.y, h0.z, h0.w, h1.x, h1.y, h1.z, h1.w,
                        h2.x, h2.y, h2.z, h2.w, h3.x, h3.y, h3.z, h3.w};
        const float* wrow = wbt + (size_t)tokid[row] * RANK * DOUTF;
        float* orow = out + (size_t)row * DOUTF;
#pragma unroll
        for (int n = 0; n < 4; ++n) {
          const int col = cb + n * 16 + ccol;
          float v = acc[m][n][j] + biasn[n];
#pragma unroll
          for (int r = 0; r < 16; ++r) v += hv[r] * wrow[(size_t)r * DOUTF + col];
          orow[col] = v;
        }
      }
    }
  }
#undef STAGE1
#undef RD_A
#undef RD_B
#undef MFMA16
#undef PH_OPEN
#undef PH_CLOSE
#undef PH_CLOSE_VM
}

// ---------------------------------------------------------------------- launch
extern "C" void kernel_launch(void* const* d_in, const int* in_sizes, int n_in,
                              void* d_out, int out_size, void* d_ws, size_t ws_size,
                              hipStream_t stream) {
  const float* x       = (const float*)d_in[0];
  const float* base_w  = (const float*)d_in[1];
  const float* base_b  = (const float*)d_in[2];
  const float* wa      = (const float*)d_in[3];
  const float* wb      = (const float*)d_in[4];
  const float* scaling = (const float*)d_in[5];
  const int*   segment = (const int*)d_in[6];
  const int*   lora_id = (const int*)d_in[7];
  float* out = (float*)d_out;

  char* ws = (char*)d_ws;
  unsigned short* xb   = (unsigned short*)ws;                                  // 64 MB
  unsigned short* wbf  = (unsigned short*)(ws + (size_t)T_TOK * DIN * 2);      // 32 MB
  float* hbuf          = (float*)(ws + (size_t)T_TOK * DIN * 2 + (size_t)DOUTF * DIN * 2);
  int* tokid           = (int*)((char*)hbuf + (size_t)T_TOK * RANK * 4);
  unsigned short* hb16 = (unsigned short*)((char*)tokid + (size_t)T_TOK * 4);

  cvt_f32_bf16<<<2048, 256, 0, stream>>>(base_w, wbf, (DOUTF * DIN) / 8);
  lora_h<<<T_TOK / 16, 256, 0, stream>>>(x, wa, scaling, segment, lora_id, hbuf, hb16,
                                         tokid, xb);
  gemm_fused<<<(T_TOK / BM) * (DOUTF / BN), 512, 0, stream>>>(xb, wbf, base_b, hbuf,
                                                              hb16, tokid, wb, out);
}